// Round 12
// baseline (261.045 us; speedup 1.0000x reference)
//
#include <hip/hip_runtime.h>
#include <math.h>

#define N_NODES 100000
#define N_EDGES 1600000
#define C_DIM 40
#define NGROUPS 6250                      // 100000 / 16 exactly

#define BSZ 256                           // nodes per bucket
#define NB  ((N_NODES + BSZ - 1) / BSZ)   // 391
#define EB  4096                          // edges per hist/scatter block
#define NBE ((N_EDGES + EB - 1) / EB)     // 391

// ---------------- workspace layout (4-byte units) ----------------
// gather arrays (REC2/H1P/H2A/H2B) are 128B-aligned: offsets are multiples of 32 units
#define OFF_DINV 0                        // float[100000]
#define OFF_BB   100000                   // int[NB+1]
#define OFF_CS   100392                   // int[NB] column sums
#define OFF_ROW  100800                   // int[N+1]
#define OFF_H    200802                   // int[NBE*NB] (ends 353683)
#define OFF_REC2 353696                   // int2[E] sorted records, 128B-aligned
#define OFF_H1P  3553696                  // ushort[N*64] bf16 h1', 128B rows, 128B-aligned
#define OFF_H2A  6753696                  // ushort[N*32] bf16 h2' cols 0-31, 64B rows, 128B-aligned
#define OFF_H2B  8353696                  // ushort[N*8]  bf16 h2' cols 32-39, 16B rows, 128B-aligned
#define OFF_AGG1 8753696                  // float[N*64]; unsorted rec aliases H1P (dead before h1p)

typedef float floatx4 __attribute__((ext_vector_type(4)));
typedef short shortx8 __attribute__((ext_vector_type(8)));

__device__ inline unsigned short f2bf(float f) {
    unsigned int u = __float_as_uint(f);
    u += 0x7FFF + ((u >> 16) & 1);        // round to nearest even
    return (unsigned short)(u >> 16);
}
__device__ inline float bflo(unsigned int u) { return __uint_as_float(u << 16); }
__device__ inline float bfhi(unsigned int u) { return __uint_as_float(u & 0xFFFF0000u); }

// ---------- per-block bucket histogram: H[b][j] + global column sums ----------
__global__ __launch_bounds__(512) void k_hist2d(const int* __restrict__ ei,
                                                int* __restrict__ H,
                                                int* __restrict__ colsum) {
    __shared__ int bins[NB];
    int t = threadIdx.x, b = blockIdx.x;
    for (int i = t; i < NB; i += 512) bins[i] = 0;
    __syncthreads();
    int base = b * EB;
    for (int i = t; i < EB; i += 512) {
        int e = base + i;
        if (e < N_EDGES) atomicAdd(&bins[ei[N_EDGES + e] >> 8], 1);
    }
    __syncthreads();
    for (int i = t; i < NB; i += 512) {
        int c = bins[i];
        H[b * NB + i] = c;
        if (c) atomicAdd(&colsum[i], c);
    }
}

// ---------- column scan (self-computes bucketBase[j] from colsum) ----------
__global__ __launch_bounds__(512) void k_colscan(int* __restrict__ H,
                                                 const int* __restrict__ colsum,
                                                 int* __restrict__ bucketBase,
                                                 int* __restrict__ rowStart) {
    __shared__ int sd[512];
    __shared__ int sbase;
    int t = threadIdx.x, j = blockIdx.x;
    int p = 0;
    for (int i = t; i < j; i += 512) p += colsum[i];
    sd[t] = p;
    __syncthreads();
    for (int off = 256; off > 0; off >>= 1) {
        if (t < off) sd[t] += sd[t + off];
        __syncthreads();
    }
    if (t == 0) sbase = sd[0];
    __syncthreads();
    int base = sbase;
    if (t == 0) {
        bucketBase[j] = base;
        if (j == NB - 1) { bucketBase[NB] = base + colsum[j]; rowStart[N_NODES] = N_EDGES; }
    }
    __syncthreads();
    int val = (t < NBE) ? H[t * NB + j] : 0;
    sd[t] = val;
    __syncthreads();
    for (int off = 1; off < 512; off <<= 1) {
        int v = (t >= off) ? sd[t - off] : 0;
        __syncthreads();
        sd[t] += v;
        __syncthreads();
    }
    if (t < NBE) H[t * NB + j] = base + sd[t] - val;
}

// ---------- scatter into bucket regions (LDS cursors, no global atomics) ----------
__global__ __launch_bounds__(512) void k_scatter(const int* __restrict__ ei,
                                                 const float* __restrict__ w,
                                                 const int* __restrict__ blockBase,
                                                 int2* __restrict__ rec) {
    __shared__ int bases[NB];
    __shared__ int cur[NB];
    int t = threadIdx.x, b = blockIdx.x;
    for (int i = t; i < NB; i += 512) { bases[i] = blockBase[b * NB + i]; cur[i] = 0; }
    __syncthreads();
    int base = b * EB;
    for (int i = t; i < EB; i += 512) {
        int e = base + i;
        if (e < N_EDGES) {
            int s = ei[e], d = ei[N_EDGES + e];
            float wv = w[e];
            int bin = d >> 8;
            int pos = bases[bin] + atomicAdd(&cur[bin], 1);
            rec[pos] = make_int2(s | ((d & 255) << 17), __float_as_int(wv));
        }
    }
}

// ---------- per-bucket counting sort; payload = w*dinv[dst]; x = src byte-offset ----------
__global__ __launch_bounds__(512) void k_bsort(const int* __restrict__ bucketBase,
                                               const int2* __restrict__ rec,
                                               int2* __restrict__ rec2,
                                               float* __restrict__ dinv,
                                               int* __restrict__ rowStart) {
    __shared__ int   cnt[256];
    __shared__ float wsum[256];
    __shared__ int   cur[256];
    __shared__ int   sd[512];
    int t = threadIdx.x, b = blockIdx.x;
    if (t < 256) { cnt[t] = 0; wsum[t] = 0.f; }
    __syncthreads();
    int r0 = bucketBase[b], r1 = bucketBase[b + 1];
    for (int i = r0 + t; i < r1; i += 512) {
        int2 rv = rec[i];
        int l = (rv.x >> 17) & 255;
        atomicAdd(&cnt[l], 1);
        atomicAdd(&wsum[l], __int_as_float(rv.y));
    }
    __syncthreads();
    int val = (t < 256) ? cnt[t] : 0;
    sd[t] = val;
    __syncthreads();
    for (int off = 1; off < 512; off <<= 1) {
        int v = (t >= off) ? sd[t - off] : 0;
        __syncthreads();
        sd[t] += v;
        __syncthreads();
    }
    float dloc = 0.f;
    if (t < 256) {
        int excl = sd[t] - val;
        cur[t] = excl;
        int node = b * BSZ + t;
        dloc = rsqrtf(1.f + wsum[t]);
        if (node < N_NODES) {
            rowStart[node] = r0 + excl;
            dinv[node] = dloc;
        }
    }
    __syncthreads();
    if (t < 256) wsum[t] = dloc;
    __syncthreads();
    for (int i = r0 + t; i < r1; i += 512) {
        int2 rv = rec[i];
        int l = (rv.x >> 17) & 255;
        float cpart = __int_as_float(rv.y) * wsum[l];   // w * dinv[dst]
        int pos = r0 + atomicAdd(&cur[l], 1);
        rec2[pos] = make_int2((rv.x & 0x1FFFF) << 7, __float_as_int(cpart));  // src*128B
    }
}

// ---------- h1' = (x @ W1) * dinv[row] via MFMA, stored bf16, 128B rows ----------
__global__ __launch_bounds__(256) void k_mm1(const float* __restrict__ x,
                                             const float* __restrict__ W1,
                                             const float* __restrict__ dinv,
                                             unsigned short* __restrict__ h1p) {
    int t = threadIdx.x, lane = t & 63, wv = t >> 6;
    int m = lane & 15, quad = lane >> 4;
    int wid = blockIdx.x * 4 + wv, nw = gridDim.x * 4;
    shortx8 B[2][4];
#pragma unroll
    for (int kc = 0; kc < 2; ++kc)
#pragma unroll
        for (int tt = 0; tt < 4; ++tt)
#pragma unroll
            for (int j = 0; j < 8; ++j) {
                int k = kc * 32 + quad * 8 + j;
                B[kc][tt][j] = (short)f2bf(W1[k * 64 + tt * 16 + m]);
            }
    for (int g = wid; g < NGROUPS; g += nw) {
        int n0 = g * 16;
        const float* xr = x + (long)(n0 + m) * 64 + quad * 8;
        floatx4 xa = ((const floatx4*)xr)[0];
        floatx4 xb = ((const floatx4*)(xr + 4))[0];
        floatx4 xc = ((const floatx4*)(xr + 32))[0];
        floatx4 xd = ((const floatx4*)(xr + 36))[0];
        shortx8 A0, A1;
#pragma unroll
        for (int j = 0; j < 4; ++j) {
            A0[j] = (short)f2bf(xa[j]);
            A0[4 + j] = (short)f2bf(xb[j]);
            A1[j] = (short)f2bf(xc[j]);
            A1[4 + j] = (short)f2bf(xd[j]);
        }
        floatx4 acc[4];
#pragma unroll
        for (int tt = 0; tt < 4; ++tt) {
            acc[tt] = (floatx4){0.f, 0.f, 0.f, 0.f};
            acc[tt] = __builtin_amdgcn_mfma_f32_16x16x32_bf16(A0, B[0][tt], acc[tt], 0, 0, 0);
            acc[tt] = __builtin_amdgcn_mfma_f32_16x16x32_bf16(A1, B[1][tt], acc[tt], 0, 0, 0);
        }
        floatx4 dv = ((const floatx4*)(dinv + n0 + quad * 4))[0];
#pragma unroll
        for (int reg = 0; reg < 4; ++reg) {
            int node = n0 + quad * 4 + reg;
            float d = dv[reg];
#pragma unroll
            for (int tt = 0; tt < 4; ++tt)
                h1p[(long)node * 64 + tt * 16 + m] = f2bf(acc[tt][reg] * d);
        }
    }
}

// ---------- agg1: 8 edge-slots x 8 lanes x 16B gather ----------
// zero-padded cache; unpredicated inner; 3 slot-groups per iter (24 edges).
__global__ __launch_bounds__(256) void k_agg1(const int* __restrict__ rowStart,
                                              const int2* __restrict__ rec2,
                                              const float* __restrict__ dinv,
                                              const unsigned short* __restrict__ h1p,
                                              float* __restrict__ agg1) {
    __shared__ int2 cache[4][80];
    int t = threadIdx.x, lane = t & 63, wv = t >> 6;
    int node = blockIdx.x * 4 + wv;
    if (node >= N_NODES) return;
    int2* wc = cache[wv];
    wc[lane] = make_int2(0, 0);
    if (lane < 16) wc[64 + lane] = make_int2(0, 0);   // tail stays zero forever
    const char* hb = (const char*)h1p;
    int eslot = lane >> 3;            // 0..7
    int c = lane & 7;
    int lo = c << 4;                  // 16B per lane, 8 lanes cover the 128B row
    float dn = dinv[node];
    float a0=0.f,a1=0.f,a2=0.f,a3=0.f,a4=0.f,a5=0.f,a6=0.f,a7=0.f;
    float b0=0.f,b1=0.f,b2=0.f,b3=0.f,b4=0.f,b5=0.f,b6=0.f,b7=0.f;
    if (eslot == 0) {
        uint4 u = *(const uint4*)(hb + ((long)node << 7) + lo);
        a0 = bflo(u.x) * dn; a1 = bfhi(u.x) * dn;
        a2 = bflo(u.y) * dn; a3 = bfhi(u.y) * dn;
        a4 = bflo(u.z) * dn; a5 = bfhi(u.z) * dn;
        a6 = bflo(u.w) * dn; a7 = bfhi(u.w) * dn;
    }
    int s0 = rowStart[node], s1 = rowStart[node + 1];
    for (int base = s0; base < s1; base += 64) {
        int idx = base + lane;
        int2 r = make_int2(0, 0);
        if (idx < s1) r = rec2[idx];
        wc[lane] = r;                                  // unconditional: zero-pads partial chunk
        __builtin_amdgcn_wave_barrier();
        int cnt = min(64, s1 - base);
        for (int j = 0; j < cnt; j += 24) {            // max idx 48+16+7 = 71 < 80
            int2 e0 = wc[j + eslot];
            int2 e1 = wc[j + 8 + eslot];
            int2 e2 = wc[j + 16 + eslot];
            float w0 = __int_as_float(e0.y);
            float w1 = __int_as_float(e1.y);
            float w2 = __int_as_float(e2.y);
            uint4 q0 = *(const uint4*)(hb + e0.x + lo);
            uint4 q1 = *(const uint4*)(hb + e1.x + lo);
            uint4 q2 = *(const uint4*)(hb + e2.x + lo);
            a0 = fmaf(bflo(q0.x), w0, a0); a1 = fmaf(bfhi(q0.x), w0, a1);
            a2 = fmaf(bflo(q0.y), w0, a2); a3 = fmaf(bfhi(q0.y), w0, a3);
            a4 = fmaf(bflo(q0.z), w0, a4); a5 = fmaf(bfhi(q0.z), w0, a5);
            a6 = fmaf(bflo(q0.w), w0, a6); a7 = fmaf(bfhi(q0.w), w0, a7);
            b0 = fmaf(bflo(q1.x), w1, b0); b1 = fmaf(bfhi(q1.x), w1, b1);
            b2 = fmaf(bflo(q1.y), w1, b2); b3 = fmaf(bfhi(q1.y), w1, b3);
            b4 = fmaf(bflo(q1.z), w1, b4); b5 = fmaf(bfhi(q1.z), w1, b5);
            b6 = fmaf(bflo(q1.w), w1, b6); b7 = fmaf(bfhi(q1.w), w1, b7);
            a0 = fmaf(bflo(q2.x), w2, a0); a1 = fmaf(bfhi(q2.x), w2, a1);
            a2 = fmaf(bflo(q2.y), w2, a2); a3 = fmaf(bfhi(q2.y), w2, a3);
            a4 = fmaf(bflo(q2.z), w2, a4); a5 = fmaf(bfhi(q2.z), w2, a5);
            a6 = fmaf(bflo(q2.w), w2, a6); a7 = fmaf(bfhi(q2.w), w2, a7);
        }
        __builtin_amdgcn_wave_barrier();
    }
    a0 += b0; a1 += b1; a2 += b2; a3 += b3;
    a4 += b4; a5 += b5; a6 += b6; a7 += b7;
    a0 += __shfl_xor(a0, 8, 64); a0 += __shfl_xor(a0, 16, 64); a0 += __shfl_xor(a0, 32, 64);
    a1 += __shfl_xor(a1, 8, 64); a1 += __shfl_xor(a1, 16, 64); a1 += __shfl_xor(a1, 32, 64);
    a2 += __shfl_xor(a2, 8, 64); a2 += __shfl_xor(a2, 16, 64); a2 += __shfl_xor(a2, 32, 64);
    a3 += __shfl_xor(a3, 8, 64); a3 += __shfl_xor(a3, 16, 64); a3 += __shfl_xor(a3, 32, 64);
    a4 += __shfl_xor(a4, 8, 64); a4 += __shfl_xor(a4, 16, 64); a4 += __shfl_xor(a4, 32, 64);
    a5 += __shfl_xor(a5, 8, 64); a5 += __shfl_xor(a5, 16, 64); a5 += __shfl_xor(a5, 32, 64);
    a6 += __shfl_xor(a6, 8, 64); a6 += __shfl_xor(a6, 16, 64); a6 += __shfl_xor(a6, 32, 64);
    a7 += __shfl_xor(a7, 8, 64); a7 += __shfl_xor(a7, 16, 64); a7 += __shfl_xor(a7, 32, 64);
    if (eslot == 0) {
        float* op = agg1 + ((long)node << 6) + (c << 3);
        *(float4*)op       = make_float4(a0, a1, a2, a3);
        *(float4*)(op + 4) = make_float4(a4, a5, a6, a7);
    }
}

// ---------- agg2: 12 edge-slots x 5 lanes x 16B gather + softmax ----------
// Lane c<4 reads uint4 from h2a (64B row); lane c==4 reads the whole 16B h2b row.
// 5 transactions/edge (was 10). 3 slot-groups per iter (36 edges). Lanes 60-63 idle (fscale).
__global__ __launch_bounds__(256) void k_agg2(const int* __restrict__ rowStart,
                                              const int2* __restrict__ rec2,
                                              const float* __restrict__ dinv,
                                              const unsigned short* __restrict__ h2a,
                                              const unsigned short* __restrict__ h2b,
                                              const float* __restrict__ b2,
                                              float* __restrict__ out) {
    __shared__ int2 cache[4][80];
    int t = threadIdx.x, lane = t & 63, wv = t >> 6;
    int node = blockIdx.x * 4 + wv;
    if (node >= N_NODES) return;
    int2* wc = cache[wv];
    wc[lane] = make_int2(0, 0);
    if (lane < 16) wc[64 + lane] = make_int2(0, 0);   // tail stays zero forever
    int eslot = lane / 5;             // 0..12 (12 = idle, lanes 60-63)
    int c = lane - eslot * 5;         // 0..4; lane c holds cols 8c..8c+7
    float fscale = (eslot < 12) ? 1.f : 0.f;
    // rec2 e.x = src*128. h2a byte = src*64 = e.x>>1; h2b byte = src*16 = e.x>>3.
    const char* gb = (c < 4) ? (const char*)h2a : (const char*)h2b;
    int sh = (c < 4) ? 1 : 3;
    int lo2 = (c < 4) ? (c << 4) : 0;
    float dn = dinv[node];
    float p0=0.f,p1=0.f,p2=0.f,p3=0.f,p4=0.f,p5=0.f,p6=0.f,p7=0.f;
    float q0=0.f,q1=0.f,q2=0.f,q3=0.f,q4=0.f,q5=0.f,q6=0.f,q7=0.f;
    if (eslot == 0) {
        uint4 u = *(const uint4*)(gb + (((long)node << 7) >> sh) + lo2);
        p0 = bflo(u.x) * dn; p1 = bfhi(u.x) * dn;
        p2 = bflo(u.y) * dn; p3 = bfhi(u.y) * dn;
        p4 = bflo(u.z) * dn; p5 = bfhi(u.z) * dn;
        p6 = bflo(u.w) * dn; p7 = bfhi(u.w) * dn;
    }
    int s0 = rowStart[node], s1 = rowStart[node + 1];
    for (int base = s0; base < s1; base += 64) {
        int idx = base + lane;
        int2 r = make_int2(0, 0);
        if (idx < s1) r = rec2[idx];
        wc[lane] = r;                                  // unconditional: zero-pads partial chunk
        __builtin_amdgcn_wave_barrier();
        int cnt = min(64, s1 - base);
        for (int j = 0; j < cnt; j += 36) {            // max idx 36+24+12 = 72 < 80
            int2 e0 = wc[j + eslot];
            int2 e1 = wc[j + 12 + eslot];
            int2 e2 = wc[j + 24 + eslot];
            float f0 = __int_as_float(e0.y) * fscale;
            float f1 = __int_as_float(e1.y) * fscale;
            float f2 = __int_as_float(e2.y) * fscale;
            uint4 u0 = *(const uint4*)(gb + (e0.x >> sh) + lo2);
            uint4 u1 = *(const uint4*)(gb + (e1.x >> sh) + lo2);
            uint4 u2 = *(const uint4*)(gb + (e2.x >> sh) + lo2);
            p0 = fmaf(bflo(u0.x), f0, p0); p1 = fmaf(bfhi(u0.x), f0, p1);
            p2 = fmaf(bflo(u0.y), f0, p2); p3 = fmaf(bfhi(u0.y), f0, p3);
            p4 = fmaf(bflo(u0.z), f0, p4); p5 = fmaf(bfhi(u0.z), f0, p5);
            p6 = fmaf(bflo(u0.w), f0, p6); p7 = fmaf(bfhi(u0.w), f0, p7);
            q0 = fmaf(bflo(u1.x), f1, q0); q1 = fmaf(bfhi(u1.x), f1, q1);
            q2 = fmaf(bflo(u1.y), f1, q2); q3 = fmaf(bfhi(u1.y), f1, q3);
            q4 = fmaf(bflo(u1.z), f1, q4); q5 = fmaf(bfhi(u1.z), f1, q5);
            q6 = fmaf(bflo(u1.w), f1, q6); q7 = fmaf(bfhi(u1.w), f1, q7);
            p0 = fmaf(bflo(u2.x), f2, p0); p1 = fmaf(bfhi(u2.x), f2, p1);
            p2 = fmaf(bflo(u2.y), f2, p2); p3 = fmaf(bfhi(u2.y), f2, p3);
            p4 = fmaf(bflo(u2.z), f2, p4); p5 = fmaf(bfhi(u2.z), f2, p5);
            p6 = fmaf(bflo(u2.w), f2, p6); p7 = fmaf(bfhi(u2.w), f2, p7);
        }
        __builtin_amdgcn_wave_barrier();
    }
    p0 += q0; p1 += q1; p2 += q2; p3 += q3;
    p4 += q4; p5 += q5; p6 += q6; p7 += q7;
    // reduce across 12 slot-groups (stride 5): +30 folds 12->6; +10,+20 fold 6->2; +5 folds 2->1.
    // Result valid on lanes 0..4.
    p0 += __shfl(p0, (lane + 30) & 63, 64);
    p1 += __shfl(p1, (lane + 30) & 63, 64);
    p2 += __shfl(p2, (lane + 30) & 63, 64);
    p3 += __shfl(p3, (lane + 30) & 63, 64);
    p4 += __shfl(p4, (lane + 30) & 63, 64);
    p5 += __shfl(p5, (lane + 30) & 63, 64);
    p6 += __shfl(p6, (lane + 30) & 63, 64);
    p7 += __shfl(p7, (lane + 30) & 63, 64);
    p0 = p0 + __shfl(p0, (lane + 10) & 63, 64) + __shfl(p0, (lane + 20) & 63, 64);
    p1 = p1 + __shfl(p1, (lane + 10) & 63, 64) + __shfl(p1, (lane + 20) & 63, 64);
    p2 = p2 + __shfl(p2, (lane + 10) & 63, 64) + __shfl(p2, (lane + 20) & 63, 64);
    p3 = p3 + __shfl(p3, (lane + 10) & 63, 64) + __shfl(p3, (lane + 20) & 63, 64);
    p4 = p4 + __shfl(p4, (lane + 10) & 63, 64) + __shfl(p4, (lane + 20) & 63, 64);
    p5 = p5 + __shfl(p5, (lane + 10) & 63, 64) + __shfl(p5, (lane + 20) & 63, 64);
    p6 = p6 + __shfl(p6, (lane + 10) & 63, 64) + __shfl(p6, (lane + 20) & 63, 64);
    p7 = p7 + __shfl(p7, (lane + 10) & 63, 64) + __shfl(p7, (lane + 20) & 63, 64);
    p0 += __shfl(p0, (lane + 5) & 63, 64);
    p1 += __shfl(p1, (lane + 5) & 63, 64);
    p2 += __shfl(p2, (lane + 5) & 63, 64);
    p3 += __shfl(p3, (lane + 5) & 63, 64);
    p4 += __shfl(p4, (lane + 5) & 63, 64);
    p5 += __shfl(p5, (lane + 5) & 63, 64);
    p6 += __shfl(p6, (lane + 5) & 63, 64);
    p7 += __shfl(p7, (lane + 5) & 63, 64);
    bool act = lane < 5;
    float4 bbA = *(const float4*)(b2 + (c << 3));
    float4 bbB = *(const float4*)(b2 + (c << 3) + 4);
    float v0 = act ? p0 + bbA.x : -INFINITY;
    float v1 = act ? p1 + bbA.y : -INFINITY;
    float v2 = act ? p2 + bbA.z : -INFINITY;
    float v3 = act ? p3 + bbA.w : -INFINITY;
    float v4 = act ? p4 + bbB.x : -INFINITY;
    float v5 = act ? p5 + bbB.y : -INFINITY;
    float v6 = act ? p6 + bbB.z : -INFINITY;
    float v7 = act ? p7 + bbB.w : -INFINITY;
    float m = fmaxf(fmaxf(fmaxf(v0, v1), fmaxf(v2, v3)),
                    fmaxf(fmaxf(v4, v5), fmaxf(v6, v7)));
    // lanes 0..7 are xor-closed under offsets 4,2,1; lanes 5..7 hold -INF
    m = fmaxf(m, __shfl_xor(m, 4, 64));
    m = fmaxf(m, __shfl_xor(m, 2, 64));
    m = fmaxf(m, __shfl_xor(m, 1, 64));
    const float LOG2E = 1.4426950408889634f;
    const float LN2   = 0.6931471805599453f;
    float s = 0.f;
    if (act) {
        s  = __builtin_amdgcn_exp2f((v0 - m) * LOG2E);
        s += __builtin_amdgcn_exp2f((v1 - m) * LOG2E);
        s += __builtin_amdgcn_exp2f((v2 - m) * LOG2E);
        s += __builtin_amdgcn_exp2f((v3 - m) * LOG2E);
        s += __builtin_amdgcn_exp2f((v4 - m) * LOG2E);
        s += __builtin_amdgcn_exp2f((v5 - m) * LOG2E);
        s += __builtin_amdgcn_exp2f((v6 - m) * LOG2E);
        s += __builtin_amdgcn_exp2f((v7 - m) * LOG2E);
    }
    s += __shfl_xor(s, 4, 64);
    s += __shfl_xor(s, 2, 64);
    s += __shfl_xor(s, 1, 64);
    float ls = m + __builtin_amdgcn_logf(s) * LN2;
    if (act) {
        float* op = out + (long)node * C_DIM + (c << 3);
        *(float4*)op       = make_float4(v0 - ls, v1 - ls, v2 - ls, v3 - ls);
        *(float4*)(op + 4) = make_float4(v4 - ls, v5 - ls, v6 - ls, v7 - ls);
    }
}

// ---------- h2' = (relu(agg1+b1) @ W2) * dinv via MFMA, split bf16 stores ----------
// cols 0-31 -> h2a (64B rows, 6.4MB), cols 32-39 -> h2b (16B rows, 1.6MB)
__global__ __launch_bounds__(256) void k_mm2(const float* __restrict__ agg1,
                                             const float* __restrict__ b1,
                                             const float* __restrict__ W2,
                                             const float* __restrict__ dinv,
                                             unsigned short* __restrict__ h2a,
                                             unsigned short* __restrict__ h2b) {
    int t = threadIdx.x, lane = t & 63, wv = t >> 6;
    int m = lane & 15, quad = lane >> 4;
    int wid = blockIdx.x * 4 + wv, nw = gridDim.x * 4;
    shortx8 B[2][3];
#pragma unroll
    for (int kc = 0; kc < 2; ++kc)
#pragma unroll
        for (int tt = 0; tt < 3; ++tt) {
            int n = tt * 16 + m;
#pragma unroll
            for (int j = 0; j < 8; ++j) {
                int k = kc * 32 + quad * 8 + j;
                B[kc][tt][j] = (n < C_DIM) ? (short)f2bf(W2[k * C_DIM + n]) : (short)0;
            }
        }
    floatx4 ba0 = ((const floatx4*)(b1 + quad * 8))[0];
    floatx4 ba1 = ((const floatx4*)(b1 + quad * 8 + 4))[0];
    floatx4 bb0 = ((const floatx4*)(b1 + 32 + quad * 8))[0];
    floatx4 bb1 = ((const floatx4*)(b1 + 32 + quad * 8 + 4))[0];
    for (int g = wid; g < NGROUPS; g += nw) {
        int n0 = g * 16;
        const float* xr = agg1 + (long)(n0 + m) * 64 + quad * 8;
        floatx4 xa = ((const floatx4*)xr)[0];
        floatx4 xb = ((const floatx4*)(xr + 4))[0];
        floatx4 xc = ((const floatx4*)(xr + 32))[0];
        floatx4 xd = ((const floatx4*)(xr + 36))[0];
        shortx8 A0, A1;
#pragma unroll
        for (int j = 0; j < 4; ++j) {
            A0[j]     = (short)f2bf(fmaxf(xa[j] + ba0[j], 0.f));
            A0[4 + j] = (short)f2bf(fmaxf(xb[j] + ba1[j], 0.f));
            A1[j]     = (short)f2bf(fmaxf(xc[j] + bb0[j], 0.f));
            A1[4 + j] = (short)f2bf(fmaxf(xd[j] + bb1[j], 0.f));
        }
        floatx4 acc[3];
#pragma unroll
        for (int tt = 0; tt < 3; ++tt) {
            acc[tt] = (floatx4){0.f, 0.f, 0.f, 0.f};
            acc[tt] = __builtin_amdgcn_mfma_f32_16x16x32_bf16(A0, B[0][tt], acc[tt], 0, 0, 0);
            acc[tt] = __builtin_amdgcn_mfma_f32_16x16x32_bf16(A1, B[1][tt], acc[tt], 0, 0, 0);
        }
        floatx4 dv = ((const floatx4*)(dinv + n0 + quad * 4))[0];
#pragma unroll
        for (int reg = 0; reg < 4; ++reg) {
            int node = n0 + quad * 4 + reg;
            float d = dv[reg];
            h2a[(long)node * 32 + m]      = f2bf(acc[0][reg] * d);
            h2a[(long)node * 32 + 16 + m] = f2bf(acc[1][reg] * d);
            if (m < 8)
                h2b[(long)node * 8 + m]   = f2bf(acc[2][reg] * d);
        }
    }
}

extern "C" void kernel_launch(void* const* d_in, const int* in_sizes, int n_in,
                              void* d_out, int out_size, void* d_ws, size_t ws_size,
                              hipStream_t stream) {
    const float* x  = (const float*)d_in[0];
    const int*   ei = (const int*)d_in[1];
    const float* w  = (const float*)d_in[2];
    const float* W1 = (const float*)d_in[3];
    const float* b1 = (const float*)d_in[4];
    const float* W2 = (const float*)d_in[5];
    const float* b2 = (const float*)d_in[6];
    float* out = (float*)d_out;

    float* wsf = (float*)d_ws;
    int*   wsi = (int*)d_ws;
    float* dinv       = wsf + OFF_DINV;
    int*   bucketBase = wsi + OFF_BB;
    int*   colsum     = wsi + OFF_CS;
    int*   rowStart   = wsi + OFF_ROW;
    int*   H          = wsi + OFF_H;
    int2*  rec2       = (int2*)(wsi + OFF_REC2);
    int2*  rec        = (int2*)(wsi + OFF_H1P);              // dead before h1p written
    unsigned short* h1p = (unsigned short*)(wsi + OFF_H1P);
    unsigned short* h2a = (unsigned short*)(wsi + OFF_H2A);
    unsigned short* h2b = (unsigned short*)(wsi + OFF_H2B);
    float* agg1       = wsf + OFF_AGG1;

    // CSR build — zero global atomics except 391-bin colsum
    hipMemsetAsync(colsum, 0, NB * sizeof(int), stream);
    k_hist2d<<<NBE, 512, 0, stream>>>(ei, H, colsum);
    k_colscan<<<NB, 512, 0, stream>>>(H, colsum, bucketBase, rowStart);
    k_scatter<<<NBE, 512, 0, stream>>>(ei, w, H, rec);
    k_bsort<<<NB, 512, 0, stream>>>(bucketBase, rec, rec2, dinv, rowStart);

    // layer 1 (MFMA matmul + gather-aggregate)
    k_mm1<<<512, 256, 0, stream>>>(x, W1, dinv, h1p);
    k_agg1<<<(N_NODES + 3) / 4, 256, 0, stream>>>(rowStart, rec2, dinv, h1p, agg1);

    // layer 2 (MFMA matmul + gather-aggregate + fused log-softmax)
    k_mm2<<<512, 256, 0, stream>>>(agg1, b1, W2, dinv, h2a, h2b);
    k_agg2<<<(N_NODES + 3) / 4, 256, 0, stream>>>(rowStart, rec2, dinv, h2a, h2b, b2, out);
}

// Round 13
// 248.695 us; speedup vs baseline: 1.0497x; 1.0497x over previous
//
#include <hip/hip_runtime.h>
#include <math.h>

#define N_NODES 100000
#define N_EDGES 1600000
#define C_DIM 40
#define NGROUPS 6250                      // 100000 / 16 exactly

#define BSZ 256                           // nodes per bucket
#define NB  ((N_NODES + BSZ - 1) / BSZ)   // 391
#define EB  4096                          // edges per hist/scatter block
#define NBE ((N_EDGES + EB - 1) / EB)     // 391

// ---------------- workspace layout (4-byte units) ----------------
// gather arrays (REC2/H1P/H2A/H2B) are 128B-aligned: offsets are multiples of 32 units
#define OFF_DINV 0                        // float[100000]
#define OFF_BB   100000                   // int[NB+1]
#define OFF_CS   100392                   // int[NB] column sums
#define OFF_ROW  100800                   // int[N+1]
#define OFF_H    200802                   // int[NBE*NB] (ends 353683)
#define OFF_REC2 353696                   // int2[E] sorted records, 128B-aligned
#define OFF_H1P  3553696                  // ushort[N*64] bf16 h1', 128B rows, 128B-aligned
#define OFF_H2A  6753696                  // ushort[N*32] bf16 h2' cols 0-31, 64B rows, 128B-aligned
#define OFF_H2B  8353696                  // ushort[N*8]  bf16 h2' cols 32-39, 16B rows, 128B-aligned
#define OFF_AGG1 8753696                  // float[N*64]; unsorted rec aliases H1P (dead before h1p)

typedef float floatx4 __attribute__((ext_vector_type(4)));
typedef short shortx8 __attribute__((ext_vector_type(8)));

__device__ inline unsigned short f2bf(float f) {
    unsigned int u = __float_as_uint(f);
    u += 0x7FFF + ((u >> 16) & 1);        // round to nearest even
    return (unsigned short)(u >> 16);
}
__device__ inline float bflo(unsigned int u) { return __uint_as_float(u << 16); }
__device__ inline float bfhi(unsigned int u) { return __uint_as_float(u & 0xFFFF0000u); }

// ---------- per-block bucket histogram (int4-vectorized dst reads) ----------
__global__ __launch_bounds__(512) void k_hist2d(const int* __restrict__ ei,
                                                int* __restrict__ H,
                                                int* __restrict__ colsum) {
    __shared__ int bins[NB];
    int t = threadIdx.x, b = blockIdx.x;
    for (int i = t; i < NB; i += 512) bins[i] = 0;
    __syncthreads();
    int base = b * EB;
    const int4* dst4 = (const int4*)(ei + N_EDGES + base);
    for (int i = t; i < EB / 4; i += 512) {
        int e4 = base + i * 4;
        if (e4 + 3 < N_EDGES) {
            int4 d = dst4[i];
            atomicAdd(&bins[d.x >> 8], 1);
            atomicAdd(&bins[d.y >> 8], 1);
            atomicAdd(&bins[d.z >> 8], 1);
            atomicAdd(&bins[d.w >> 8], 1);
        } else {
#pragma unroll
            for (int k = 0; k < 4; ++k) {
                int e = e4 + k;
                if (e < N_EDGES) atomicAdd(&bins[ei[N_EDGES + e] >> 8], 1);
            }
        }
    }
    __syncthreads();
    for (int i = t; i < NB; i += 512) {
        int c = bins[i];
        H[b * NB + i] = c;
        if (c) atomicAdd(&colsum[i], c);
    }
}

// ---------- column scan (self-computes bucketBase[j] from colsum) ----------
__global__ __launch_bounds__(512) void k_colscan(int* __restrict__ H,
                                                 const int* __restrict__ colsum,
                                                 int* __restrict__ bucketBase,
                                                 int* __restrict__ rowStart) {
    __shared__ int sd[512];
    __shared__ int sbase;
    int t = threadIdx.x, j = blockIdx.x;
    int p = 0;
    for (int i = t; i < j; i += 512) p += colsum[i];
    sd[t] = p;
    __syncthreads();
    for (int off = 256; off > 0; off >>= 1) {
        if (t < off) sd[t] += sd[t + off];
        __syncthreads();
    }
    if (t == 0) sbase = sd[0];
    __syncthreads();
    int base = sbase;
    if (t == 0) {
        bucketBase[j] = base;
        if (j == NB - 1) { bucketBase[NB] = base + colsum[j]; rowStart[N_NODES] = N_EDGES; }
    }
    __syncthreads();
    int val = (t < NBE) ? H[t * NB + j] : 0;
    sd[t] = val;
    __syncthreads();
    for (int off = 1; off < 512; off <<= 1) {
        int v = (t >= off) ? sd[t - off] : 0;
        __syncthreads();
        sd[t] += v;
        __syncthreads();
    }
    if (t < NBE) H[t * NB + j] = base + sd[t] - val;
}

// ---------- scatter into bucket regions (int4/float4 reads, LDS cursors) ----------
__global__ __launch_bounds__(512) void k_scatter(const int* __restrict__ ei,
                                                 const float* __restrict__ w,
                                                 const int* __restrict__ blockBase,
                                                 int2* __restrict__ rec) {
    __shared__ int bases[NB];
    __shared__ int cur[NB];
    int t = threadIdx.x, b = blockIdx.x;
    for (int i = t; i < NB; i += 512) { bases[i] = blockBase[b * NB + i]; cur[i] = 0; }
    __syncthreads();
    int base = b * EB;
    const int4*   src4 = (const int4*)(ei + base);
    const int4*   dst4 = (const int4*)(ei + N_EDGES + base);
    const float4* wv4  = (const float4*)(w + base);
    for (int i = t; i < EB / 4; i += 512) {
        int e4 = base + i * 4;
        if (e4 + 3 < N_EDGES) {
            int4 s = src4[i];
            int4 d = dst4[i];
            float4 wv = wv4[i];
            int bin, pos;
            bin = d.x >> 8; pos = bases[bin] + atomicAdd(&cur[bin], 1);
            rec[pos] = make_int2(s.x | ((d.x & 255) << 17), __float_as_int(wv.x));
            bin = d.y >> 8; pos = bases[bin] + atomicAdd(&cur[bin], 1);
            rec[pos] = make_int2(s.y | ((d.y & 255) << 17), __float_as_int(wv.y));
            bin = d.z >> 8; pos = bases[bin] + atomicAdd(&cur[bin], 1);
            rec[pos] = make_int2(s.z | ((d.z & 255) << 17), __float_as_int(wv.z));
            bin = d.w >> 8; pos = bases[bin] + atomicAdd(&cur[bin], 1);
            rec[pos] = make_int2(s.w | ((d.w & 255) << 17), __float_as_int(wv.w));
        } else {
#pragma unroll
            for (int k = 0; k < 4; ++k) {
                int e = e4 + k;
                if (e < N_EDGES) {
                    int ss = ei[e], dd = ei[N_EDGES + e];
                    float wvv = w[e];
                    int bin = dd >> 8;
                    int pos = bases[bin] + atomicAdd(&cur[bin], 1);
                    rec[pos] = make_int2(ss | ((dd & 255) << 17), __float_as_int(wvv));
                }
            }
        }
    }
}

// ---------- per-bucket counting sort; payload = w*dinv[dst]; x = src byte-offset ----------
__global__ __launch_bounds__(512) void k_bsort(const int* __restrict__ bucketBase,
                                               const int2* __restrict__ rec,
                                               int2* __restrict__ rec2,
                                               float* __restrict__ dinv,
                                               int* __restrict__ rowStart) {
    __shared__ int   cnt[256];
    __shared__ float wsum[256];
    __shared__ int   cur[256];
    __shared__ int   sd[512];
    int t = threadIdx.x, b = blockIdx.x;
    if (t < 256) { cnt[t] = 0; wsum[t] = 0.f; }
    __syncthreads();
    int r0 = bucketBase[b], r1 = bucketBase[b + 1];
    for (int i = r0 + t; i < r1; i += 512) {
        int2 rv = rec[i];
        int l = (rv.x >> 17) & 255;
        atomicAdd(&cnt[l], 1);
        atomicAdd(&wsum[l], __int_as_float(rv.y));
    }
    __syncthreads();
    int val = (t < 256) ? cnt[t] : 0;
    sd[t] = val;
    __syncthreads();
    for (int off = 1; off < 512; off <<= 1) {
        int v = (t >= off) ? sd[t - off] : 0;
        __syncthreads();
        sd[t] += v;
        __syncthreads();
    }
    float dloc = 0.f;
    if (t < 256) {
        int excl = sd[t] - val;
        cur[t] = excl;
        int node = b * BSZ + t;
        dloc = rsqrtf(1.f + wsum[t]);
        if (node < N_NODES) {
            rowStart[node] = r0 + excl;
            dinv[node] = dloc;
        }
    }
    __syncthreads();
    if (t < 256) wsum[t] = dloc;
    __syncthreads();
    for (int i = r0 + t; i < r1; i += 512) {
        int2 rv = rec[i];
        int l = (rv.x >> 17) & 255;
        float cpart = __int_as_float(rv.y) * wsum[l];   // w * dinv[dst]
        int pos = r0 + atomicAdd(&cur[l], 1);
        rec2[pos] = make_int2((rv.x & 0x1FFFF) << 7, __float_as_int(cpart));  // src*128B
    }
}

// ---------- h1' = (x @ W1) * dinv[row] via MFMA, stored bf16, 128B rows ----------
__global__ __launch_bounds__(256) void k_mm1(const float* __restrict__ x,
                                             const float* __restrict__ W1,
                                             const float* __restrict__ dinv,
                                             unsigned short* __restrict__ h1p) {
    int t = threadIdx.x, lane = t & 63, wv = t >> 6;
    int m = lane & 15, quad = lane >> 4;
    int wid = blockIdx.x * 4 + wv, nw = gridDim.x * 4;
    shortx8 B[2][4];
#pragma unroll
    for (int kc = 0; kc < 2; ++kc)
#pragma unroll
        for (int tt = 0; tt < 4; ++tt)
#pragma unroll
            for (int j = 0; j < 8; ++j) {
                int k = kc * 32 + quad * 8 + j;
                B[kc][tt][j] = (short)f2bf(W1[k * 64 + tt * 16 + m]);
            }
    for (int g = wid; g < NGROUPS; g += nw) {
        int n0 = g * 16;
        const float* xr = x + (long)(n0 + m) * 64 + quad * 8;
        floatx4 xa = ((const floatx4*)xr)[0];
        floatx4 xb = ((const floatx4*)(xr + 4))[0];
        floatx4 xc = ((const floatx4*)(xr + 32))[0];
        floatx4 xd = ((const floatx4*)(xr + 36))[0];
        shortx8 A0, A1;
#pragma unroll
        for (int j = 0; j < 4; ++j) {
            A0[j] = (short)f2bf(xa[j]);
            A0[4 + j] = (short)f2bf(xb[j]);
            A1[j] = (short)f2bf(xc[j]);
            A1[4 + j] = (short)f2bf(xd[j]);
        }
        floatx4 acc[4];
#pragma unroll
        for (int tt = 0; tt < 4; ++tt) {
            acc[tt] = (floatx4){0.f, 0.f, 0.f, 0.f};
            acc[tt] = __builtin_amdgcn_mfma_f32_16x16x32_bf16(A0, B[0][tt], acc[tt], 0, 0, 0);
            acc[tt] = __builtin_amdgcn_mfma_f32_16x16x32_bf16(A1, B[1][tt], acc[tt], 0, 0, 0);
        }
        floatx4 dv = ((const floatx4*)(dinv + n0 + quad * 4))[0];
#pragma unroll
        for (int reg = 0; reg < 4; ++reg) {
            int node = n0 + quad * 4 + reg;
            float d = dv[reg];
#pragma unroll
            for (int tt = 0; tt < 4; ++tt)
                h1p[(long)node * 64 + tt * 16 + m] = f2bf(acc[tt][reg] * d);
        }
    }
}

// ---------- agg1: 8 edge-slots x 8 lanes x 16B gather ----------
// zero-padded cache; unpredicated inner; 3 slot-groups per iter (24 edges).
__global__ __launch_bounds__(256) void k_agg1(const int* __restrict__ rowStart,
                                              const int2* __restrict__ rec2,
                                              const float* __restrict__ dinv,
                                              const unsigned short* __restrict__ h1p,
                                              float* __restrict__ agg1) {
    __shared__ int2 cache[4][80];
    int t = threadIdx.x, lane = t & 63, wv = t >> 6;
    int node = blockIdx.x * 4 + wv;
    if (node >= N_NODES) return;
    int2* wc = cache[wv];
    wc[lane] = make_int2(0, 0);
    if (lane < 16) wc[64 + lane] = make_int2(0, 0);   // tail stays zero forever
    const char* hb = (const char*)h1p;
    int eslot = lane >> 3;            // 0..7
    int c = lane & 7;
    int lo = c << 4;                  // 16B per lane, 8 lanes cover the 128B row
    float dn = dinv[node];
    float a0=0.f,a1=0.f,a2=0.f,a3=0.f,a4=0.f,a5=0.f,a6=0.f,a7=0.f;
    float b0=0.f,b1=0.f,b2=0.f,b3=0.f,b4=0.f,b5=0.f,b6=0.f,b7=0.f;
    if (eslot == 0) {
        uint4 u = *(const uint4*)(hb + ((long)node << 7) + lo);
        a0 = bflo(u.x) * dn; a1 = bfhi(u.x) * dn;
        a2 = bflo(u.y) * dn; a3 = bfhi(u.y) * dn;
        a4 = bflo(u.z) * dn; a5 = bfhi(u.z) * dn;
        a6 = bflo(u.w) * dn; a7 = bfhi(u.w) * dn;
    }
    int s0 = rowStart[node], s1 = rowStart[node + 1];
    for (int base = s0; base < s1; base += 64) {
        int idx = base + lane;
        int2 r = make_int2(0, 0);
        if (idx < s1) r = rec2[idx];
        wc[lane] = r;                                  // unconditional: zero-pads partial chunk
        __builtin_amdgcn_wave_barrier();
        int cnt = min(64, s1 - base);
        for (int j = 0; j < cnt; j += 24) {            // max idx 48+16+7 = 71 < 80
            int2 e0 = wc[j + eslot];
            int2 e1 = wc[j + 8 + eslot];
            int2 e2 = wc[j + 16 + eslot];
            float w0 = __int_as_float(e0.y);
            float w1 = __int_as_float(e1.y);
            float w2 = __int_as_float(e2.y);
            uint4 q0 = *(const uint4*)(hb + e0.x + lo);
            uint4 q1 = *(const uint4*)(hb + e1.x + lo);
            uint4 q2 = *(const uint4*)(hb + e2.x + lo);
            a0 = fmaf(bflo(q0.x), w0, a0); a1 = fmaf(bfhi(q0.x), w0, a1);
            a2 = fmaf(bflo(q0.y), w0, a2); a3 = fmaf(bfhi(q0.y), w0, a3);
            a4 = fmaf(bflo(q0.z), w0, a4); a5 = fmaf(bfhi(q0.z), w0, a5);
            a6 = fmaf(bflo(q0.w), w0, a6); a7 = fmaf(bfhi(q0.w), w0, a7);
            b0 = fmaf(bflo(q1.x), w1, b0); b1 = fmaf(bfhi(q1.x), w1, b1);
            b2 = fmaf(bflo(q1.y), w1, b2); b3 = fmaf(bfhi(q1.y), w1, b3);
            b4 = fmaf(bflo(q1.z), w1, b4); b5 = fmaf(bfhi(q1.z), w1, b5);
            b6 = fmaf(bflo(q1.w), w1, b6); b7 = fmaf(bfhi(q1.w), w1, b7);
            a0 = fmaf(bflo(q2.x), w2, a0); a1 = fmaf(bfhi(q2.x), w2, a1);
            a2 = fmaf(bflo(q2.y), w2, a2); a3 = fmaf(bfhi(q2.y), w2, a3);
            a4 = fmaf(bflo(q2.z), w2, a4); a5 = fmaf(bfhi(q2.z), w2, a5);
            a6 = fmaf(bflo(q2.w), w2, a6); a7 = fmaf(bfhi(q2.w), w2, a7);
        }
        __builtin_amdgcn_wave_barrier();
    }
    a0 += b0; a1 += b1; a2 += b2; a3 += b3;
    a4 += b4; a5 += b5; a6 += b6; a7 += b7;
    a0 += __shfl_xor(a0, 8, 64); a0 += __shfl_xor(a0, 16, 64); a0 += __shfl_xor(a0, 32, 64);
    a1 += __shfl_xor(a1, 8, 64); a1 += __shfl_xor(a1, 16, 64); a1 += __shfl_xor(a1, 32, 64);
    a2 += __shfl_xor(a2, 8, 64); a2 += __shfl_xor(a2, 16, 64); a2 += __shfl_xor(a2, 32, 64);
    a3 += __shfl_xor(a3, 8, 64); a3 += __shfl_xor(a3, 16, 64); a3 += __shfl_xor(a3, 32, 64);
    a4 += __shfl_xor(a4, 8, 64); a4 += __shfl_xor(a4, 16, 64); a4 += __shfl_xor(a4, 32, 64);
    a5 += __shfl_xor(a5, 8, 64); a5 += __shfl_xor(a5, 16, 64); a5 += __shfl_xor(a5, 32, 64);
    a6 += __shfl_xor(a6, 8, 64); a6 += __shfl_xor(a6, 16, 64); a6 += __shfl_xor(a6, 32, 64);
    a7 += __shfl_xor(a7, 8, 64); a7 += __shfl_xor(a7, 16, 64); a7 += __shfl_xor(a7, 32, 64);
    if (eslot == 0) {
        float* op = agg1 + ((long)node << 6) + (c << 3);
        *(float4*)op       = make_float4(a0, a1, a2, a3);
        *(float4*)(op + 4) = make_float4(a4, a5, a6, a7);
    }
}

// ---------- agg2: 6 edge-slots x 10 lanes x 8B gather + softmax (round-10 shape) ----------
__global__ __launch_bounds__(256) void k_agg2(const int* __restrict__ rowStart,
                                              const int2* __restrict__ rec2,
                                              const float* __restrict__ dinv,
                                              const unsigned short* __restrict__ h2a,
                                              const unsigned short* __restrict__ h2b,
                                              const float* __restrict__ b2,
                                              float* __restrict__ out) {
    __shared__ int2 cache[4][80];
    int t = threadIdx.x, lane = t & 63, wv = t >> 6;
    int node = blockIdx.x * 4 + wv;
    if (node >= N_NODES) return;
    int2* wc = cache[wv];
    wc[lane] = make_int2(0, 0);
    if (lane < 16) wc[64 + lane] = make_int2(0, 0);
    int eslot = lane / 10;            // 0..6 (6 = idle group, lanes 60-63)
    int c = lane - eslot * 10;        // 0..9; lane c holds cols 4c..4c+3
    float fscale = (eslot < 6) ? 1.f : 0.f;
    // rec2 e.x = src*128. h2a byte = src*64 = e.x>>1 (uint2 at c*8); h2b byte = src*16 = e.x>>3.
    const char* gb = (c < 8) ? (const char*)h2a : (const char*)h2b;
    int sh = (c < 8) ? 1 : 3;
    int lo2 = (c < 8) ? (c << 3) : ((c - 8) << 3);
    float dn = dinv[node];
    float p0 = 0.f, p1 = 0.f, p2 = 0.f, p3 = 0.f;
    float r0a = 0.f, r1a = 0.f, r2a = 0.f, r3a = 0.f;
    if (eslot == 0) {
        uint2 u = *(const uint2*)(gb + (((long)node << 7) >> sh) + lo2);
        p0 = bflo(u.x) * dn; p1 = bfhi(u.x) * dn;
        p2 = bflo(u.y) * dn; p3 = bfhi(u.y) * dn;
    }
    int s0 = rowStart[node], s1 = rowStart[node + 1];
    for (int base = s0; base < s1; base += 64) {
        int idx = base + lane;
        int2 r = make_int2(0, 0);
        if (idx < s1) r = rec2[idx];
        wc[lane] = r;
        __builtin_amdgcn_wave_barrier();
        int cnt = min(64, s1 - base);
        for (int j = 0; j < cnt; j += 18) {            // max idx 54+12+6 = 72 < 80
            int2 e0 = wc[j + eslot];
            int2 e1 = wc[j + 6 + eslot];
            int2 e2 = wc[j + 12 + eslot];
            float f0 = __int_as_float(e0.y) * fscale;
            float f1 = __int_as_float(e1.y) * fscale;
            float f2 = __int_as_float(e2.y) * fscale;
            uint2 u0 = *(const uint2*)(gb + (e0.x >> sh) + lo2);
            uint2 u1 = *(const uint2*)(gb + (e1.x >> sh) + lo2);
            uint2 u2 = *(const uint2*)(gb + (e2.x >> sh) + lo2);
            p0 = fmaf(bflo(u0.x), f0, p0); p1 = fmaf(bfhi(u0.x), f0, p1);
            p2 = fmaf(bflo(u0.y), f0, p2); p3 = fmaf(bfhi(u0.y), f0, p3);
            r0a = fmaf(bflo(u1.x), f1, r0a); r1a = fmaf(bfhi(u1.x), f1, r1a);
            r2a = fmaf(bflo(u1.y), f1, r2a); r3a = fmaf(bfhi(u1.y), f1, r3a);
            p0 = fmaf(bflo(u2.x), f2, p0); p1 = fmaf(bfhi(u2.x), f2, p1);
            p2 = fmaf(bflo(u2.y), f2, p2); p3 = fmaf(bfhi(u2.y), f2, p3);
        }
        __builtin_amdgcn_wave_barrier();
    }
    p0 += r0a; p1 += r1a; p2 += r2a; p3 += r3a;
    p0 += __shfl(p0, (lane + 30) & 63, 64);
    p1 += __shfl(p1, (lane + 30) & 63, 64);
    p2 += __shfl(p2, (lane + 30) & 63, 64);
    p3 += __shfl(p3, (lane + 30) & 63, 64);
    p0 = p0 + __shfl(p0, (lane + 10) & 63, 64) + __shfl(p0, (lane + 20) & 63, 64);
    p1 = p1 + __shfl(p1, (lane + 10) & 63, 64) + __shfl(p1, (lane + 20) & 63, 64);
    p2 = p2 + __shfl(p2, (lane + 10) & 63, 64) + __shfl(p2, (lane + 20) & 63, 64);
    p3 = p3 + __shfl(p3, (lane + 10) & 63, 64) + __shfl(p3, (lane + 20) & 63, 64);
    bool act = lane < 10;
    float4 bb = *(const float4*)(b2 + (c << 2));
    float v0 = act ? p0 + bb.x : -INFINITY;
    float v1 = act ? p1 + bb.y : -INFINITY;
    float v2 = act ? p2 + bb.z : -INFINITY;
    float v3 = act ? p3 + bb.w : -INFINITY;
    float m = fmaxf(fmaxf(v0, v1), fmaxf(v2, v3));
#pragma unroll
    for (int off = 8; off; off >>= 1) m = fmaxf(m, __shfl_xor(m, off, 64));
    const float LOG2E = 1.4426950408889634f;
    const float LN2   = 0.6931471805599453f;
    float s = 0.f;
    if (act) {
        s  = __builtin_amdgcn_exp2f((v0 - m) * LOG2E);
        s += __builtin_amdgcn_exp2f((v1 - m) * LOG2E);
        s += __builtin_amdgcn_exp2f((v2 - m) * LOG2E);
        s += __builtin_amdgcn_exp2f((v3 - m) * LOG2E);
    }
#pragma unroll
    for (int off = 8; off; off >>= 1) s += __shfl_xor(s, off, 64);
    float ls = m + __builtin_amdgcn_logf(s) * LN2;
    if (act) {
        *(float4*)(out + (long)node * C_DIM + (c << 2)) =
            make_float4(v0 - ls, v1 - ls, v2 - ls, v3 - ls);
    }
}

// ---------- h2' = (relu(agg1+b1) @ W2) * dinv via MFMA, split bf16 stores ----------
// cols 0-31 -> h2a (64B rows, 6.4MB), cols 32-39 -> h2b (16B rows, 1.6MB)
__global__ __launch_bounds__(256) void k_mm2(const float* __restrict__ agg1,
                                             const float* __restrict__ b1,
                                             const float* __restrict__ W2,
                                             const float* __restrict__ dinv,
                                             unsigned short* __restrict__ h2a,
                                             unsigned short* __restrict__ h2b) {
    int t = threadIdx.x, lane = t & 63, wv = t >> 6;
    int m = lane & 15, quad = lane >> 4;
    int wid = blockIdx.x * 4 + wv, nw = gridDim.x * 4;
    shortx8 B[2][3];
#pragma unroll
    for (int kc = 0; kc < 2; ++kc)
#pragma unroll
        for (int tt = 0; tt < 3; ++tt) {
            int n = tt * 16 + m;
#pragma unroll
            for (int j = 0; j < 8; ++j) {
                int k = kc * 32 + quad * 8 + j;
                B[kc][tt][j] = (n < C_DIM) ? (short)f2bf(W2[k * C_DIM + n]) : (short)0;
            }
        }
    floatx4 ba0 = ((const floatx4*)(b1 + quad * 8))[0];
    floatx4 ba1 = ((const floatx4*)(b1 + quad * 8 + 4))[0];
    floatx4 bb0 = ((const floatx4*)(b1 + 32 + quad * 8))[0];
    floatx4 bb1 = ((const floatx4*)(b1 + 32 + quad * 8 + 4))[0];
    for (int g = wid; g < NGROUPS; g += nw) {
        int n0 = g * 16;
        const float* xr = agg1 + (long)(n0 + m) * 64 + quad * 8;
        floatx4 xa = ((const floatx4*)xr)[0];
        floatx4 xb = ((const floatx4*)(xr + 4))[0];
        floatx4 xc = ((const floatx4*)(xr + 32))[0];
        floatx4 xd = ((const floatx4*)(xr + 36))[0];
        shortx8 A0, A1;
#pragma unroll
        for (int j = 0; j < 4; ++j) {
            A0[j]     = (short)f2bf(fmaxf(xa[j] + ba0[j], 0.f));
            A0[4 + j] = (short)f2bf(fmaxf(xb[j] + ba1[j], 0.f));
            A1[j]     = (short)f2bf(fmaxf(xc[j] + bb0[j], 0.f));
            A1[4 + j] = (short)f2bf(fmaxf(xd[j] + bb1[j], 0.f));
        }
        floatx4 acc[3];
#pragma unroll
        for (int tt = 0; tt < 3; ++tt) {
            acc[tt] = (floatx4){0.f, 0.f, 0.f, 0.f};
            acc[tt] = __builtin_amdgcn_mfma_f32_16x16x32_bf16(A0, B[0][tt], acc[tt], 0, 0, 0);
            acc[tt] = __builtin_amdgcn_mfma_f32_16x16x32_bf16(A1, B[1][tt], acc[tt], 0, 0, 0);
        }
        floatx4 dv = ((const floatx4*)(dinv + n0 + quad * 4))[0];
#pragma unroll
        for (int reg = 0; reg < 4; ++reg) {
            int node = n0 + quad * 4 + reg;
            float d = dv[reg];
            h2a[(long)node * 32 + m]      = f2bf(acc[0][reg] * d);
            h2a[(long)node * 32 + 16 + m] = f2bf(acc[1][reg] * d);
            if (m < 8)
                h2b[(long)node * 8 + m]   = f2bf(acc[2][reg] * d);
        }
    }
}

extern "C" void kernel_launch(void* const* d_in, const int* in_sizes, int n_in,
                              void* d_out, int out_size, void* d_ws, size_t ws_size,
                              hipStream_t stream) {
    const float* x  = (const float*)d_in[0];
    const int*   ei = (const int*)d_in[1];
    const float* w  = (const float*)d_in[2];
    const float* W1 = (const float*)d_in[3];
    const float* b1 = (const float*)d_in[4];
    const float* W2 = (const float*)d_in[5];
    const float* b2 = (const float*)d_in[6];
    float* out = (float*)d_out;

    float* wsf = (float*)d_ws;
    int*   wsi = (int*)d_ws;
    float* dinv       = wsf + OFF_DINV;
    int*   bucketBase = wsi + OFF_BB;
    int*   colsum     = wsi + OFF_CS;
    int*   rowStart   = wsi + OFF_ROW;
    int*   H          = wsi + OFF_H;
    int2*  rec2       = (int2*)(wsi + OFF_REC2);
    int2*  rec        = (int2*)(wsi + OFF_H1P);              // dead before h1p written
    unsigned short* h1p = (unsigned short*)(wsi + OFF_H1P);
    unsigned short* h2a = (unsigned short*)(wsi + OFF_H2A);
    unsigned short* h2b = (unsigned short*)(wsi + OFF_H2B);
    float* agg1       = wsf + OFF_AGG1;

    // CSR build — zero global atomics except 391-bin colsum
    hipMemsetAsync(colsum, 0, NB * sizeof(int), stream);
    k_hist2d<<<NBE, 512, 0, stream>>>(ei, H, colsum);
    k_colscan<<<NB, 512, 0, stream>>>(H, colsum, bucketBase, rowStart);
    k_scatter<<<NBE, 512, 0, stream>>>(ei, w, H, rec);
    k_bsort<<<NB, 512, 0, stream>>>(bucketBase, rec, rec2, dinv, rowStart);

    // layer 1 (MFMA matmul + gather-aggregate)
    k_mm1<<<512, 256, 0, stream>>>(x, W1, dinv, h1p);
    k_agg1<<<(N_NODES + 3) / 4, 256, 0, stream>>>(rowStart, rec2, dinv, h1p, agg1);

    // layer 2 (MFMA matmul + gather-aggregate + fused log-softmax)
    k_mm2<<<512, 256, 0, stream>>>(agg1, b1, W2, dinv, h2a, h2b);
    k_agg2<<<(N_NODES + 3) / 4, 256, 0, stream>>>(rowStart, rec2, dinv, h2a, h2b, b2, out);
}